// Round 1
// baseline (654.961 us; speedup 1.0000x reference)
//
#include <hip/hip_runtime.h>

// Problem constants (fixed by the reference).
#define BB   32
#define TT   2048
#define FF   512
#define KK   1024
#define DD   512
#define TAIL 512            // (1-g)^512 <= (0.95)^512 ~ 4e-12: exact enough vs 5.8e-2 threshold
#define RWS  8              // timesteps per block
#define NCH  (TAIL / RWS)   // 64 chunks
#define LN_EPS 1e-5f

// g = clip(sigmoid(w1*cos(t1)cos(p1) + w2*cos(t2)cos(p2) + b_g), 0.05, 0.75)
__device__ __forceinline__ float compute_g(const float* th1, const float* ph1,
                                           const float* th2, const float* ph2,
                                           const float* w1, const float* w2,
                                           const float* bg) {
    float z1 = cosf(*th1) * cosf(*ph1);
    float z2 = cosf(*th2) * cosf(*ph2);
    float s  = (*w1) * z1 + (*w2) * z2 + (*bg);
    float sg = 1.0f / (1.0f + expf(-s));
    return fminf(fmaxf(sg, 0.05f), 0.75f);
}

// One block = 8 timesteps of one batch. Fused: x->proj->base->LN->weighted partial.
// NOTE: alpha*cal_scalar is constant across d for a given (b,t) and LayerNorm
// subtracts the d-mean, so it cancels EXACTLY -> never computed.
__global__ __launch_bounds__(256) void fused_chunk(
    const float* __restrict__ x,   const float* __restrict__ Pw,
    const float* __restrict__ Ww,  const float* __restrict__ Wb,
    const float* __restrict__ bvec,const float* __restrict__ lng,
    const float* __restrict__ lnb,
    const float* th1, const float* ph1, const float* th2, const float* ph2,
    const float* w1p, const float* w2p, const float* bgp,
    float* __restrict__ partial) {

    __shared__ float xs[FF * RWS];   // x transposed [f][r]; reused as base [r][d] (both 4096 floats)
    __shared__ float ps[KK * RWS];   // proj transposed [k][r]

    const int tid   = threadIdx.x;
    const int chunk = blockIdx.x;
    const int bb    = blockIdx.y;
    const int t0    = TT - TAIL + chunk * RWS;

    const float g   = compute_g(th1, ph1, th2, ph2, w1p, w2p, bgp);
    const float omg = 1.0f - g;

    float* pout = partial + ((size_t)bb * NCH + chunk) * DD;

    // Early exit: newest row weight = g*(1-g)^(TT-1-(t0+RWS-1)).
    // Skipped contribution bounded by (1-g)^n * max|LN| < 1e-12 * ~23 -> negligible.
    const float wtop = g * powf(omg, (float)(TT - (t0 + RWS)));
    if (wtop < 1e-12f) {
        for (int d = tid; d < DD; d += 256) pout[d] = 0.0f;
        return;
    }

    // ---- stage x tile, transposed [f][r] so GEMM1 A-reads are one b128 across rows ----
    for (int i = tid; i < RWS * FF / 4; i += 256) {
        const int r  = i >> 7;            // / (FF/4)
        const int f4 = i & (FF / 4 - 1);
        const float4 v = *(const float4*)(x + ((size_t)bb * TT + t0 + r) * FF + (size_t)f4 * 4);
        const int f = f4 * 4;
        xs[(f + 0) * RWS + r] = v.x;
        xs[(f + 1) * RWS + r] = v.y;
        xs[(f + 2) * RWS + r] = v.z;
        xs[(f + 3) * RWS + r] = v.w;
    }
    __syncthreads();

    // ---- GEMM1: proj[8][1024] = x[8][512] . Pw^T  (Pw is [K][F]) ----
    {
        const int rg = tid & 1;    // 2 row-groups of 4 rows
        const int kg = tid >> 1;   // 128 col-groups of 8 cols
        float acc[4][8];
        #pragma unroll
        for (int i = 0; i < 4; ++i)
            #pragma unroll
            for (int j = 0; j < 8; ++j) acc[i][j] = 0.0f;

        const float* pwb = Pw + (size_t)kg * 8 * FF;
        for (int f = 0; f < FF; f += 4) {
            float4 am[4];
            #pragma unroll
            for (int m = 0; m < 4; ++m)
                am[m] = *(const float4*)&xs[(f + m) * RWS + rg * 4];
            #pragma unroll
            for (int j = 0; j < 8; ++j) {
                const float4 bv = *(const float4*)(pwb + (size_t)j * FF + f);
                acc[0][j] += am[0].x * bv.x + am[1].x * bv.y + am[2].x * bv.z + am[3].x * bv.w;
                acc[1][j] += am[0].y * bv.x + am[1].y * bv.y + am[2].y * bv.z + am[3].y * bv.w;
                acc[2][j] += am[0].z * bv.x + am[1].z * bv.y + am[2].z * bv.z + am[3].z * bv.w;
                acc[3][j] += am[0].w * bv.x + am[1].w * bv.y + am[2].w * bv.z + am[3].w * bv.w;
            }
        }
        #pragma unroll
        for (int j = 0; j < 8; ++j)
            #pragma unroll
            for (int i = 0; i < 4; ++i)
                ps[(kg * 8 + j) * RWS + rg * 4 + i] = acc[i][j];
    }
    __syncthreads();

    // ---- GEMM2: base[8][512] = proj[8][1024] . Ww^T + (Wb + b)  (Ww is [D][K]) ----
    {
        const int rg = tid & 1;    // 2 row-groups of 4 rows
        const int dg = tid >> 1;   // 128 col-groups of 4 cols
        float acc[4][4];
        #pragma unroll
        for (int i = 0; i < 4; ++i)
            #pragma unroll
            for (int j = 0; j < 4; ++j) acc[i][j] = 0.0f;

        for (int k = 0; k < KK; k += 4) {
            float4 am[4];
            #pragma unroll
            for (int m = 0; m < 4; ++m)
                am[m] = *(const float4*)&ps[(k + m) * RWS + rg * 4];
            #pragma unroll
            for (int j = 0; j < 4; ++j) {
                const float4 bv = *(const float4*)(Ww + (size_t)(dg * 4 + j) * KK + k);
                acc[0][j] += am[0].x * bv.x + am[1].x * bv.y + am[2].x * bv.z + am[3].x * bv.w;
                acc[1][j] += am[0].y * bv.x + am[1].y * bv.y + am[2].y * bv.z + am[3].y * bv.w;
                acc[2][j] += am[0].z * bv.x + am[1].z * bv.y + am[2].z * bv.z + am[3].z * bv.w;
                acc[3][j] += am[0].w * bv.x + am[1].w * bv.y + am[2].w * bv.z + am[3].w * bv.w;
            }
        }
        // write base into xs region as [r][d]
        #pragma unroll
        for (int j = 0; j < 4; ++j) {
            const int d = dg * 4 + j;
            const float bias = Wb[d] + bvec[d];
            #pragma unroll
            for (int i = 0; i < 4; ++i)
                xs[(rg * 4 + i) * DD + d] = acc[i][j] + bias;
        }
    }
    __syncthreads();

    // ---- LayerNorm per row (two-pass, biased var) + EMA weight ----
    {
        const int r    = tid >> 5;   // 8 rows x 32 lanes
        const int lane = tid & 31;
        float s = 0.0f;
        #pragma unroll
        for (int j = 0; j < DD / 32; ++j) s += xs[r * DD + lane + j * 32];
        #pragma unroll
        for (int off = 16; off >= 1; off >>= 1) s += __shfl_xor(s, off);
        const float mu = s * (1.0f / DD);

        float ss = 0.0f;
        #pragma unroll
        for (int j = 0; j < DD / 32; ++j) {
            const float v = xs[r * DD + lane + j * 32] - mu;
            ss += v * v;
        }
        #pragma unroll
        for (int off = 16; off >= 1; off >>= 1) ss += __shfl_xor(ss, off);
        const float rstd = rsqrtf(ss * (1.0f / DD) + LN_EPS);

        const float wr = g * powf(omg, (float)(TT - 1 - (t0 + r)));
        #pragma unroll
        for (int j = 0; j < DD / 32; ++j) {
            const int d = lane + j * 32;
            const float v = xs[r * DD + d];
            xs[r * DD + d] = wr * ((v - mu) * rstd * lng[d] + lnb[d]);
        }
    }
    __syncthreads();

    // ---- per-chunk weighted partial sum over the 8 rows ----
    for (int d = tid; d < DD; d += 256) {
        float p = 0.0f;
        #pragma unroll
        for (int r = 0; r < RWS; ++r) p += xs[r * DD + d];
        pout[d] = p;
    }
}

// h[b][d] = sum over chunks of partials
__global__ __launch_bounds__(512) void ema_reduce(const float* __restrict__ partial,
                                                  float* __restrict__ out) {
    const int b = blockIdx.x;
    const int d = threadIdx.x;
    float s = 0.0f;
    for (int c = 0; c < NCH; ++c)
        s += partial[((size_t)b * NCH + c) * DD + d];
    out[b * DD + d] = s;
}

extern "C" void kernel_launch(void* const* d_in, const int* in_sizes, int n_in,
                              void* d_out, int out_size, void* d_ws, size_t ws_size,
                              hipStream_t stream) {
    const float* x   = (const float*)d_in[0];
    const float* Pw  = (const float*)d_in[1];
    const float* Ww  = (const float*)d_in[2];
    const float* Wb  = (const float*)d_in[3];
    const float* bv  = (const float*)d_in[4];
    const float* lng = (const float*)d_in[5];
    const float* lnb = (const float*)d_in[6];
    // d_in[7] = alpha: unused — alpha*cal_scalar is constant over d, LayerNorm cancels it exactly.
    const float* th1 = (const float*)d_in[8];
    const float* ph1 = (const float*)d_in[9];
    const float* th2 = (const float*)d_in[10];
    const float* ph2 = (const float*)d_in[11];
    const float* w1  = (const float*)d_in[12];
    const float* w2  = (const float*)d_in[13];
    const float* bg  = (const float*)d_in[14];

    float* partial = (float*)d_ws;   // [BB][NCH][DD] f32 = 4 MB

    dim3 grid(NCH, BB);
    fused_chunk<<<grid, 256, 0, stream>>>(x, Pw, Ww, Wb, bv, lng, lnb,
                                          th1, ph1, th2, ph2, w1, w2, bg, partial);
    ema_reduce<<<BB, DD, 0, stream>>>(partial, (float*)d_out);
}

// Round 2
// 254.678 us; speedup vs baseline: 2.5717x; 2.5717x over previous
//
#include <hip/hip_runtime.h>

// Problem constants (fixed by the reference).
#define BB   32
#define TT   2048
#define FF   512
#define KK   1024
#define DD   512
#define NC   64          // chunk slots; block (c,bg) handles timesteps t=TT-1-(c+64j), j=0..7
#define BROWS 4          // batches per block (weight reuse across 4 rows)
#define NBG  (BB/BROWS)  // 8 batch-groups
#define LN_EPS 1e-5f
#define WCUT 1e-12f      // drop terms with EMA weight < 1e-12 (bounded err ~5e-11 << 5.8e-2 thr)

// g = clip(sigmoid(w1*cos(t1)cos(p1) + w2*cos(t2)cos(p2) + b_g), 0.05, 0.75)
__device__ __forceinline__ float compute_g(const float* th1, const float* ph1,
                                           const float* th2, const float* ph2,
                                           const float* w1, const float* w2,
                                           const float* bg) {
    float z1 = cosf(*th1) * cosf(*ph1);
    float z2 = cosf(*th2) * cosf(*ph2);
    float s  = (*w1) * z1 + (*w2) * z2 + (*bg);
    float sg = 1.0f / (1.0f + expf(-s));
    return fminf(fmaxf(sg, 0.05f), 0.75f);
}

// One block: 4 batch-rows at timestep t (looped over strided chunk indices).
// Fused x->proj->base->LN->weighted accumulate. alpha*cal cancels in LN exactly.
__global__ __launch_bounds__(512) void fused_rows(
    const float* __restrict__ x,   const float* __restrict__ Pw,
    const float* __restrict__ Ww,  const float* __restrict__ Wb,
    const float* __restrict__ bvec,const float* __restrict__ lng,
    const float* __restrict__ lnb,
    const float* th1, const float* ph1, const float* th2, const float* ph2,
    const float* w1p, const float* w2p, const float* bgp,
    float* __restrict__ partial) {

    __shared__ float xs[BROWS * FF];      // x rows [r][f]            (8 KB)
    __shared__ float ps[KK * BROWS];      // proj transposed [k][r]   (16 KB)
    __shared__ float red[8][BROWS][2];    // per-wave LN partials

    const int tid = threadIdx.x;
    const int c   = blockIdx.x;           // chunk slot 0..63
    const int bg  = blockIdx.y;           // batch group 0..7
    const int d   = tid;                  // 512 threads <-> 512 d

    const float g   = compute_g(th1, ph1, th2, ph2, w1p, w2p, bgp);
    const float omg = 1.0f - g;

    // thread-invariant per-d params
    const float bias = Wb[d] + bvec[d];
    const float gam  = lng[d];
    const float bet  = lnb[d];

    float hacc[BROWS] = {0.f, 0.f, 0.f, 0.f};
    bool  any = false;

    for (int j = 0; j < TT / (NC * 4) * 2; ++j) {   // j = 0..7 (512/64)
        const int   cj = c + NC * j;
        const float wj = g * powf(omg, (float)cj);
        if (wj < WCUT) break;                        // monotone in j
        any = true;
        const int t = TT - 1 - cj;

        // ---- stage 4 x rows (coalesced float4) ----
        for (int i = tid; i < BROWS * FF / 4; i += 512) {
            const int r  = i >> 7;
            const int f4 = i & (FF / 4 - 1);
            const float4 v = *(const float4*)(x + ((size_t)(bg * BROWS + r) * TT + t) * FF + (size_t)f4 * 4);
            *(float4*)&xs[r * FF + f4 * 4] = v;
        }
        __syncthreads();

        // ---- GEMM1: thread owns k = tid and k = tid+512; all 4 rows reuse the Pw row ----
        {
            float a0[BROWS] = {0.f, 0.f, 0.f, 0.f};
            float a1[BROWS] = {0.f, 0.f, 0.f, 0.f};
            const float* p0 = Pw + (size_t)tid * FF;
            const float* p1 = Pw + (size_t)(tid + 512) * FF;
            for (int f = 0; f < FF; f += 4) {
                const float4 w0 = *(const float4*)(p0 + f);
                const float4 w1 = *(const float4*)(p1 + f);
                #pragma unroll
                for (int r = 0; r < BROWS; ++r) {
                    const float4 xv = *(const float4*)&xs[r * FF + f];   // broadcast
                    a0[r] += xv.x * w0.x + xv.y * w0.y + xv.z * w0.z + xv.w * w0.w;
                    a1[r] += xv.x * w1.x + xv.y * w1.y + xv.z * w1.z + xv.w * w1.w;
                }
            }
            // conflict-free b128 writes: ps[k][0..3]
            *(float4*)&ps[(size_t)tid * 4]         = make_float4(a0[0], a0[1], a0[2], a0[3]);
            *(float4*)&ps[(size_t)(tid + 512) * 4] = make_float4(a1[0], a1[1], a1[2], a1[3]);
        }
        __syncthreads();

        // ---- GEMM2: thread owns output column d for all 4 rows ----
        float v4[BROWS] = {bias, bias, bias, bias};
        {
            const float* wwr = Ww + (size_t)d * KK;
            for (int k = 0; k < KK; k += 4) {
                const float4 wv = *(const float4*)(wwr + k);
                const float4 q0 = *(const float4*)&ps[(size_t)(k + 0) * 4];  // broadcast
                const float4 q1 = *(const float4*)&ps[(size_t)(k + 1) * 4];
                const float4 q2 = *(const float4*)&ps[(size_t)(k + 2) * 4];
                const float4 q3 = *(const float4*)&ps[(size_t)(k + 3) * 4];
                v4[0] += wv.x * q0.x + wv.y * q1.x + wv.z * q2.x + wv.w * q3.x;
                v4[1] += wv.x * q0.y + wv.y * q1.y + wv.z * q2.y + wv.w * q3.y;
                v4[2] += wv.x * q0.z + wv.y * q1.z + wv.z * q2.z + wv.w * q3.z;
                v4[3] += wv.x * q0.w + wv.y * q1.w + wv.z * q2.w + wv.w * q3.w;
            }
        }

        // ---- LN stats across 512 threads (per row), E[x^2]-mu^2 (no cancellation risk here) ----
        {
            float s[BROWS], ss[BROWS];
            #pragma unroll
            for (int r = 0; r < BROWS; ++r) { s[r] = v4[r]; ss[r] = v4[r] * v4[r]; }
            #pragma unroll
            for (int off = 32; off >= 1; off >>= 1) {
                #pragma unroll
                for (int r = 0; r < BROWS; ++r) {
                    s[r]  += __shfl_xor(s[r],  off);
                    ss[r] += __shfl_xor(ss[r], off);
                }
            }
            const int wave = tid >> 6, lane = tid & 63;
            if (lane == 0) {
                #pragma unroll
                for (int r = 0; r < BROWS; ++r) { red[wave][r][0] = s[r]; red[wave][r][1] = ss[r]; }
            }
            __syncthreads();
            #pragma unroll
            for (int r = 0; r < BROWS; ++r) {
                float S = 0.f, SS = 0.f;
                #pragma unroll
                for (int w = 0; w < 8; ++w) { S += red[w][r][0]; SS += red[w][r][1]; }
                const float mu   = S * (1.0f / DD);
                const float var  = SS * (1.0f / DD) - mu * mu;
                const float rstd = rsqrtf(var + LN_EPS);
                hacc[r] += wj * ((v4[r] - mu) * rstd * gam + bet);
            }
        }
        // next iteration's staging is gated by its own __syncthreads
        __syncthreads();
    }

    if (!any) return;   // reduce kernel uses the identical j=0 predicate

    float* pout = partial + (((size_t)c * NBG + bg) * BROWS) * DD;
    #pragma unroll
    for (int r = 0; r < BROWS; ++r) pout[r * DD + d] = hacc[r];
}

// h[b][d] = sum over active chunk slots (same predicate as fused_rows)
__global__ __launch_bounds__(512) void ema_reduce(
    const float* __restrict__ partial, float* __restrict__ out,
    const float* th1, const float* ph1, const float* th2, const float* ph2,
    const float* w1p, const float* w2p, const float* bgp) {
    const int b = blockIdx.x;
    const int d = threadIdx.x;
    const int bg = b >> 2, r = b & 3;
    const float g   = compute_g(th1, ph1, th2, ph2, w1p, w2p, bgp);
    const float omg = 1.0f - g;
    float s = 0.f;
    for (int c = 0; c < NC; ++c) {
        if (g * powf(omg, (float)c) < WCUT) break;   // identical expression -> identical predicate
        s += partial[(((size_t)c * NBG + bg) * BROWS + r) * DD + d];
    }
    out[(size_t)b * DD + d] = s;
}

extern "C" void kernel_launch(void* const* d_in, const int* in_sizes, int n_in,
                              void* d_out, int out_size, void* d_ws, size_t ws_size,
                              hipStream_t stream) {
    const float* x   = (const float*)d_in[0];
    const float* Pw  = (const float*)d_in[1];
    const float* Ww  = (const float*)d_in[2];
    const float* Wb  = (const float*)d_in[3];
    const float* bv  = (const float*)d_in[4];
    const float* lng = (const float*)d_in[5];
    const float* lnb = (const float*)d_in[6];
    // d_in[7] = alpha: unused — alpha*cal_scalar is constant over d; LayerNorm cancels it exactly.
    const float* th1 = (const float*)d_in[8];
    const float* ph1 = (const float*)d_in[9];
    const float* th2 = (const float*)d_in[10];
    const float* ph2 = (const float*)d_in[11];
    const float* w1  = (const float*)d_in[12];
    const float* w2  = (const float*)d_in[13];
    const float* bg  = (const float*)d_in[14];

    float* partial = (float*)d_ws;   // [NC][NBG][BROWS][DD] f32 = 4 MB

    dim3 grid(NC, NBG);
    fused_rows<<<grid, 512, 0, stream>>>(x, Pw, Ww, Wb, bv, lng, lnb,
                                         th1, ph1, th2, ph2, w1, w2, bg, partial);
    ema_reduce<<<BB, DD, 0, stream>>>(partial, (float*)d_out,
                                      th1, ph1, th2, ph2, w1, w2, bg);
}

// Round 3
// 128.056 us; speedup vs baseline: 5.1146x; 1.9888x over previous
//
#include <hip/hip_runtime.h>

// Problem constants (fixed by the reference).
#define BB   32
#define TT   2048
#define FF   512
#define KK   1024
#define DD   512
#define NC   64          // chunk slots; block (c,bg) handles timesteps t=TT-1-(c+64j)
#define BROWS 2          // batches per block
#define NBG  (BB/BROWS)  // 16 batch-groups
#define LN_EPS 1e-5f
#define WCUT 1e-12f      // drop terms with EMA weight < 1e-12 (bounded err ~5e-11 << 5.8e-2 thr)

// g = clip(sigmoid(w1*cos(t1)cos(p1) + w2*cos(t2)cos(p2) + b_g), 0.05, 0.75)
__device__ __forceinline__ float compute_g(const float* th1, const float* ph1,
                                           const float* th2, const float* ph2,
                                           const float* w1, const float* w2,
                                           const float* bg) {
    float z1 = cosf(*th1) * cosf(*ph1);
    float z2 = cosf(*th2) * cosf(*ph2);
    float s  = (*w1) * z1 + (*w2) * z2 + (*bg);
    float sg = 1.0f / (1.0f + expf(-s));
    return fminf(fmaxf(sg, 0.05f), 0.75f);
}

// ---- C = Ww @ Pw : [D,K]x[K,F] -> [D,F].  base = x @ C^T, exact reassociation. ----
// Grid: 256 blocks, each a 32(d) x 32(f) tile over K=1024.
__global__ __launch_bounds__(256) void weight_merge(
    const float* __restrict__ Pw, const float* __restrict__ Ww,
    float* __restrict__ C) {
    __shared__ float pws[64][32];     // Pw k-chunk x f-tile
    const int tid = threadIdx.x;
    const int d0  = (blockIdx.x >> 4) * 32;
    const int f0  = (blockIdx.x & 15) * 32;
    const int dl  = tid >> 3;         // 0..31
    const int fg  = tid & 7;          // 0..7 -> 4 f each
    const float* wwr = Ww + (size_t)(d0 + dl) * KK;

    float acc[4] = {0.f, 0.f, 0.f, 0.f};
    for (int k0 = 0; k0 < KK; k0 += 64) {
        {   // stage Pw[k0..k0+63][f0..f0+31], coalesced float4
            const int row = tid >> 3;
            const int col = (tid & 7) * 4;
            *(float4*)&pws[row][col]      = *(const float4*)(Pw + (size_t)(k0 + row)      * FF + f0 + col);
            *(float4*)&pws[row + 32][col] = *(const float4*)(Pw + (size_t)(k0 + row + 32) * FF + f0 + col);
        }
        __syncthreads();
        #pragma unroll 4
        for (int k = 0; k < 64; k += 4) {
            const float4 wv = *(const float4*)(wwr + k0 + k);   // L1-broadcast across 8 lanes
            const float4 p0 = *(const float4*)&pws[k + 0][fg * 4];
            const float4 p1 = *(const float4*)&pws[k + 1][fg * 4];
            const float4 p2 = *(const float4*)&pws[k + 2][fg * 4];
            const float4 p3 = *(const float4*)&pws[k + 3][fg * 4];
            acc[0] += wv.x * p0.x + wv.y * p1.x + wv.z * p2.x + wv.w * p3.x;
            acc[1] += wv.x * p0.y + wv.y * p1.y + wv.z * p2.y + wv.w * p3.y;
            acc[2] += wv.x * p0.z + wv.y * p1.z + wv.z * p2.z + wv.w * p3.z;
            acc[3] += wv.x * p0.w + wv.y * p1.w + wv.z * p2.w + wv.w * p3.w;
        }
        __syncthreads();
    }
    *(float4*)(C + (size_t)(d0 + dl) * FF + f0 + fg * 4) = *(float4*)acc;
}

// ---- fused: base = x.C^T + bias -> LN -> EMA-weighted partial. ----
// Block (c,bg): 2 batch rows, timesteps t = TT-1-(c+64j). 512 threads = 512 d.
// alpha*cal_scalar is d-constant -> cancels exactly in LayerNorm -> never computed.
__global__ __launch_bounds__(512) void fused_base(
    const float* __restrict__ x,   const float* __restrict__ C,
    const float* __restrict__ Wb,  const float* __restrict__ bvec,
    const float* __restrict__ lng, const float* __restrict__ lnb,
    const float* th1, const float* ph1, const float* th2, const float* ph2,
    const float* w1p, const float* w2p, const float* bgp,
    float* __restrict__ partial) {

    __shared__ float xs[BROWS * FF];
    __shared__ float red[8][BROWS][2];

    const int tid = threadIdx.x;
    const int c   = blockIdx.x;
    const int bg  = blockIdx.y;
    const int d   = tid;

    const float g   = compute_g(th1, ph1, th2, ph2, w1p, w2p, bgp);
    const float omg = 1.0f - g;

    const float bias = Wb[d] + bvec[d];
    const float gam  = lng[d];
    const float bet  = lnb[d];
    const float* crow = C + (size_t)d * FF;

    float hacc[BROWS] = {0.f, 0.f};
    bool  any = false;

    for (int j = 0; j < TT / NC; ++j) {
        const int cj = c + NC * j;
        if (cj >= TT) break;
        const float wj = g * powf(omg, (float)cj);
        if (wj < WCUT) break;                       // monotone in j
        any = true;
        const int t = TT - 1 - cj;

        // stage 2 x rows (coalesced float4)
        for (int i = tid; i < BROWS * FF / 4; i += 512) {
            const int r  = i >> 7;
            const int f4 = (i & 127) * 4;
            *(float4*)&xs[r * FF + f4] =
                *(const float4*)(x + ((size_t)(bg * BROWS + r) * TT + t) * FF + f4);
        }
        __syncthreads();

        // base[d] for both rows: stream C row, broadcast x from LDS. 4 accums/row for ILP.
        float a0[4] = {bias, 0.f, 0.f, 0.f};
        float a1[4] = {bias, 0.f, 0.f, 0.f};
        #pragma unroll 4
        for (int f = 0; f < FF; f += 16) {
            const float4 c0 = *(const float4*)(crow + f);
            const float4 c1 = *(const float4*)(crow + f + 4);
            const float4 c2 = *(const float4*)(crow + f + 8);
            const float4 c3 = *(const float4*)(crow + f + 12);
            const float4 x00 = *(const float4*)&xs[f];
            const float4 x01 = *(const float4*)&xs[f + 4];
            const float4 x02 = *(const float4*)&xs[f + 8];
            const float4 x03 = *(const float4*)&xs[f + 12];
            const float4 x10 = *(const float4*)&xs[FF + f];
            const float4 x11 = *(const float4*)&xs[FF + f + 4];
            const float4 x12 = *(const float4*)&xs[FF + f + 8];
            const float4 x13 = *(const float4*)&xs[FF + f + 12];
            a0[0] += c0.x * x00.x + c0.y * x00.y + c0.z * x00.z + c0.w * x00.w;
            a0[1] += c1.x * x01.x + c1.y * x01.y + c1.z * x01.z + c1.w * x01.w;
            a0[2] += c2.x * x02.x + c2.y * x02.y + c2.z * x02.z + c2.w * x02.w;
            a0[3] += c3.x * x03.x + c3.y * x03.y + c3.z * x03.z + c3.w * x03.w;
            a1[0] += c0.x * x10.x + c0.y * x10.y + c0.z * x10.z + c0.w * x10.w;
            a1[1] += c1.x * x11.x + c1.y * x11.y + c1.z * x11.z + c1.w * x11.w;
            a1[2] += c2.x * x12.x + c2.y * x12.y + c2.z * x12.z + c2.w * x12.w;
            a1[3] += c3.x * x13.x + c3.y * x13.y + c3.z * x13.z + c3.w * x13.w;
        }
        const float v0 = (a0[0] + a0[1]) + (a0[2] + a0[3]);
        const float v1 = (a1[0] + a1[1]) + (a1[2] + a1[3]);

        // LN stats across 512 threads (E[x^2]-mu^2, fp32 — values O(few), no cancellation risk)
        {
            float s0 = v0, q0 = v0 * v0, s1 = v1, q1 = v1 * v1;
            #pragma unroll
            for (int off = 32; off >= 1; off >>= 1) {
                s0 += __shfl_xor(s0, off);  q0 += __shfl_xor(q0, off);
                s1 += __shfl_xor(s1, off);  q1 += __shfl_xor(q1, off);
            }
            const int wave = tid >> 6, lane = tid & 63;
            if (lane == 0) {
                red[wave][0][0] = s0; red[wave][0][1] = q0;
                red[wave][1][0] = s1; red[wave][1][1] = q1;
            }
            __syncthreads();
            float S0 = 0.f, Q0 = 0.f, S1 = 0.f, Q1 = 0.f;
            #pragma unroll
            for (int w = 0; w < 8; ++w) {
                S0 += red[w][0][0]; Q0 += red[w][0][1];
                S1 += red[w][1][0]; Q1 += red[w][1][1];
            }
            const float mu0 = S0 * (1.0f / DD);
            const float mu1 = S1 * (1.0f / DD);
            const float r0  = rsqrtf(Q0 * (1.0f / DD) - mu0 * mu0 + LN_EPS);
            const float r1  = rsqrtf(Q1 * (1.0f / DD) - mu1 * mu1 + LN_EPS);
            hacc[0] += wj * ((v0 - mu0) * r0 * gam + bet);
            hacc[1] += wj * ((v1 - mu1) * r1 * gam + bet);
        }
        __syncthreads();   // protect xs and red for next j
    }

    if (!any) return;   // reduce kernel uses the identical c-predicate

    float* pout = partial + ((size_t)c * BB + bg * BROWS) * DD;
    pout[d]      = hacc[0];
    pout[DD + d] = hacc[1];
}

// h[b][d] = sum over active chunk slots (identical predicate as fused_base j=0)
__global__ __launch_bounds__(512) void ema_reduce(
    const float* __restrict__ partial, float* __restrict__ out,
    const float* th1, const float* ph1, const float* th2, const float* ph2,
    const float* w1p, const float* w2p, const float* bgp) {
    const int b = blockIdx.x;
    const int d = threadIdx.x;
    const float g   = compute_g(th1, ph1, th2, ph2, w1p, w2p, bgp);
    const float omg = 1.0f - g;
    float s = 0.f;
    for (int c = 0; c < NC; ++c) {
        if (g * powf(omg, (float)c) < WCUT) break;   // same float expr -> same predicate
        s += partial[((size_t)c * BB + b) * DD + d];
    }
    out[(size_t)b * DD + d] = s;
}

extern "C" void kernel_launch(void* const* d_in, const int* in_sizes, int n_in,
                              void* d_out, int out_size, void* d_ws, size_t ws_size,
                              hipStream_t stream) {
    const float* x   = (const float*)d_in[0];
    const float* Pw  = (const float*)d_in[1];
    const float* Ww  = (const float*)d_in[2];
    const float* Wb  = (const float*)d_in[3];
    const float* bv  = (const float*)d_in[4];
    const float* lng = (const float*)d_in[5];
    const float* lnb = (const float*)d_in[6];
    // d_in[7] = alpha: unused — alpha*cal_scalar is d-constant; LayerNorm cancels it exactly.
    const float* th1 = (const float*)d_in[8];
    const float* ph1 = (const float*)d_in[9];
    const float* th2 = (const float*)d_in[10];
    const float* ph2 = (const float*)d_in[11];
    const float* w1  = (const float*)d_in[12];
    const float* w2  = (const float*)d_in[13];
    const float* bg  = (const float*)d_in[14];

    float* C       = (float*)d_ws;              // [D][F] = 1 MB
    float* partial = C + (size_t)DD * FF;       // [NC][BB][DD] = 4 MB

    weight_merge<<<256, 256, 0, stream>>>(Pw, Ww, C);

    dim3 grid(NC, NBG);
    fused_base<<<grid, 512, 0, stream>>>(x, C, Wb, bv, lng, lnb,
                                         th1, ph1, th2, ph2, w1, w2, bg, partial);
    ema_reduce<<<BB, DD, 0, stream>>>(partial, (float*)d_out,
                                      th1, ph1, th2, ph2, w1, w2, bg);
}

// Round 4
// 78.560 us; speedup vs baseline: 8.3370x; 1.6300x over previous
//
#include <hip/hip_runtime.h>

// Problem constants (fixed by the reference).
#define BB   32
#define TT   2048
#define FF   512
#define KK   1024
#define DD   512
#define NC   64          // chunk slots; block (c,bg) handles timesteps t=TT-1-(c+64j)
#define BROWS 2          // batches per block
#define NBG  (BB/BROWS)  // 16 batch-groups
#define LN_EPS 1e-5f
#define WCUT 1e-12f      // drop terms with EMA weight < 1e-12 (bounded err ~5e-11 << 5.8e-2 thr)

// g = clip(sigmoid(w1*cos(t1)cos(p1) + w2*cos(t2)cos(p2) + b_g), 0.05, 0.75)
__device__ __forceinline__ float compute_g(const float* th1, const float* ph1,
                                           const float* th2, const float* ph2,
                                           const float* w1, const float* w2,
                                           const float* bg) {
    float z1 = cosf(*th1) * cosf(*ph1);
    float z2 = cosf(*th2) * cosf(*ph2);
    float s  = (*w1) * z1 + (*w2) * z2 + (*bg);
    float sg = 1.0f / (1.0f + expf(-s));
    return fminf(fmaxf(sg, 0.05f), 0.75f);
}

// ---- CT[f][d] = sum_k Ww[d][k] * Pw[k][f]  (C transposed, so fused_base reads coalesce) ----
// Tile: 16 d x 32 f over K=1024. Grid (32,16) = 512 blocks, 256 threads.
__global__ __launch_bounds__(256) void weight_merge(
    const float* __restrict__ Pw, const float* __restrict__ Ww,
    float* __restrict__ CT) {
    __shared__ float pws[64][32];    // Pw k-chunk x f-tile (8 KB)
    __shared__ float tr[32][17];     // transpose staging (f x d, padded)

    const int tid = threadIdx.x;
    const int d0  = blockIdx.x * 16;
    const int f0  = blockIdx.y * 32;
    const int dl  = tid >> 4;        // 0..15
    const int fl  = tid & 15;        // 0..15 -> f-pair f0+2*fl, +1
    const float* wwr = Ww + (size_t)(d0 + dl) * KK;

    float acc0 = 0.f, acc1 = 0.f;
    for (int k0 = 0; k0 < KK; k0 += 64) {
        {   // stage Pw[k0..k0+63][f0..f0+31], coalesced float4
            const int row = tid >> 3;
            const int col = (tid & 7) * 4;
            *(float4*)&pws[row][col]      = *(const float4*)(Pw + (size_t)(k0 + row)      * FF + f0 + col);
            *(float4*)&pws[row + 32][col] = *(const float4*)(Pw + (size_t)(k0 + row + 32) * FF + f0 + col);
        }
        __syncthreads();
        #pragma unroll 4
        for (int k = 0; k < 64; k += 4) {
            const float4 wv = *(const float4*)(wwr + k0 + k);   // 16 lanes share a row
            const float2 p0 = *(const float2*)&pws[k + 0][fl * 2];
            const float2 p1 = *(const float2*)&pws[k + 1][fl * 2];
            const float2 p2 = *(const float2*)&pws[k + 2][fl * 2];
            const float2 p3 = *(const float2*)&pws[k + 3][fl * 2];
            acc0 += wv.x * p0.x + wv.y * p1.x + wv.z * p2.x + wv.w * p3.x;
            acc1 += wv.x * p0.y + wv.y * p1.y + wv.z * p2.y + wv.w * p3.y;
        }
        __syncthreads();
    }
    // transpose through LDS so the CT store is coalesced
    tr[fl * 2][dl]     = acc0;
    tr[fl * 2 + 1][dl] = acc1;
    __syncthreads();
    if (tid < 128) {
        const int f  = tid >> 2;
        const int dq = (tid & 3) * 4;
        float4 v = make_float4(tr[f][dq], tr[f][dq + 1], tr[f][dq + 2], tr[f][dq + 3]);
        *(float4*)(CT + (size_t)(f0 + f) * DD + d0 + dq) = v;
    }
}

// ---- fused: base = x.C^T + bias -> LN -> EMA-weighted partial. ----
// Block (c,bg): 2 batch rows, timesteps t = TT-1-(c+64j). 512 threads.
// Compute phase: 4 f-quarters x 128 d-quads, coalesced CT reads; LDS k-reduce.
// alpha*cal_scalar is d-constant -> cancels exactly in LayerNorm -> never computed.
__global__ __launch_bounds__(512) void fused_base(
    const float* __restrict__ x,   const float* __restrict__ CT,
    const float* __restrict__ Wb,  const float* __restrict__ bvec,
    const float* __restrict__ lng, const float* __restrict__ lnb,
    const float* th1, const float* ph1, const float* th2, const float* ph2,
    const float* w1p, const float* w2p, const float* bgp,
    float* __restrict__ partial) {

    __shared__ float xs[BROWS][FF];          // 4 KB
    __shared__ float red2[4][BROWS][DD];     // 16 KB k-split partials
    __shared__ float redw[8][BROWS][2];      // LN wave partials

    const int tid = threadIdx.x;
    const int c   = blockIdx.x;
    const int bg  = blockIdx.y;
    const int fh  = tid >> 7;                // f-quarter 0..3
    const int d4  = (tid & 127) << 2;        // d-quad base
    const int d   = tid;                     // LN-phase d

    const float g   = compute_g(th1, ph1, th2, ph2, w1p, w2p, bgp);
    const float omg = 1.0f - g;

    const float bias = Wb[d] + bvec[d];
    const float gam  = lng[d];
    const float bet  = lnb[d];

    float hacc[BROWS] = {0.f, 0.f};
    bool  any = false;

    for (int j = 0; j < TT / NC; ++j) {
        const int cj = c + NC * j;
        if (cj >= TT) break;
        const float wj = g * powf(omg, (float)cj);
        if (wj < WCUT) break;                // monotone in j
        any = true;
        const int t = TT - 1 - cj;

        // stage 2 x rows (coalesced float4)
        for (int i = tid; i < BROWS * FF / 4; i += 512) {
            const int r  = i >> 7;
            const int f4 = (i & 127) * 4;
            *(float4*)&xs[r][f4] =
                *(const float4*)(x + ((size_t)(bg * BROWS + r) * TT + t) * FF + f4);
        }
        __syncthreads();

        // partial dot over this thread's f-quarter: 4 d x 2 rows
        float4 a0 = make_float4(0.f, 0.f, 0.f, 0.f);
        float4 a1 = make_float4(0.f, 0.f, 0.f, 0.f);
        {
            const float* ctp = CT + (size_t)(fh * 128) * DD + d4;
            const float* xr0 = &xs[0][fh * 128];
            const float* xr1 = &xs[1][fh * 128];
            #pragma unroll 2
            for (int f = 0; f < 128; f += 4) {
                const float4 xv0 = *(const float4*)(xr0 + f);   // LDS broadcast
                const float4 xv1 = *(const float4*)(xr1 + f);
                const float4 c0 = *(const float4*)(ctp + (size_t)(f + 0) * DD);
                const float4 c1 = *(const float4*)(ctp + (size_t)(f + 1) * DD);
                const float4 c2 = *(const float4*)(ctp + (size_t)(f + 2) * DD);
                const float4 c3 = *(const float4*)(ctp + (size_t)(f + 3) * DD);
                a0.x += xv0.x * c0.x + xv0.y * c1.x + xv0.z * c2.x + xv0.w * c3.x;
                a0.y += xv0.x * c0.y + xv0.y * c1.y + xv0.z * c2.y + xv0.w * c3.y;
                a0.z += xv0.x * c0.z + xv0.y * c1.z + xv0.z * c2.z + xv0.w * c3.z;
                a0.w += xv0.x * c0.w + xv0.y * c1.w + xv0.z * c2.w + xv0.w * c3.w;
                a1.x += xv1.x * c0.x + xv1.y * c1.x + xv1.z * c2.x + xv1.w * c3.x;
                a1.y += xv1.x * c0.y + xv1.y * c1.y + xv1.z * c2.y + xv1.w * c3.y;
                a1.z += xv1.x * c0.z + xv1.y * c1.z + xv1.z * c2.z + xv1.w * c3.z;
                a1.w += xv1.x * c0.w + xv1.y * c1.w + xv1.z * c2.w + xv1.w * c3.w;
            }
        }
        *(float4*)&red2[fh][0][d4] = a0;
        *(float4*)&red2[fh][1][d4] = a1;
        __syncthreads();

        // k-reduce + LN for d = tid, both rows
        float v0 = bias, v1 = bias;
        #pragma unroll
        for (int q = 0; q < 4; ++q) { v0 += red2[q][0][d]; v1 += red2[q][1][d]; }
        {
            float s0 = v0, q0 = v0 * v0, s1 = v1, q1 = v1 * v1;
            #pragma unroll
            for (int off = 32; off >= 1; off >>= 1) {
                s0 += __shfl_xor(s0, off);  q0 += __shfl_xor(q0, off);
                s1 += __shfl_xor(s1, off);  q1 += __shfl_xor(q1, off);
            }
            const int wave = tid >> 6, lane = tid & 63;
            if (lane == 0) {
                redw[wave][0][0] = s0; redw[wave][0][1] = q0;
                redw[wave][1][0] = s1; redw[wave][1][1] = q1;
            }
            __syncthreads();
            float S0 = 0.f, Q0 = 0.f, S1 = 0.f, Q1 = 0.f;
            #pragma unroll
            for (int w = 0; w < 8; ++w) {
                S0 += redw[w][0][0]; Q0 += redw[w][0][1];
                S1 += redw[w][1][0]; Q1 += redw[w][1][1];
            }
            const float mu0 = S0 * (1.0f / DD);
            const float mu1 = S1 * (1.0f / DD);
            const float r0  = rsqrtf(Q0 * (1.0f / DD) - mu0 * mu0 + LN_EPS);
            const float r1  = rsqrtf(Q1 * (1.0f / DD) - mu1 * mu1 + LN_EPS);
            hacc[0] += wj * ((v0 - mu0) * r0 * gam + bet);
            hacc[1] += wj * ((v1 - mu1) * r1 * gam + bet);
        }
        __syncthreads();   // protect xs/red2/redw for next j
    }

    if (!any) return;   // reduce kernel uses the identical c-predicate

    float* pout = partial + ((size_t)c * BB + bg * BROWS) * DD;
    pout[d]      = hacc[0];
    pout[DD + d] = hacc[1];
}

// h[b][d] = sum over active chunk slots (identical predicate as fused_base j=0)
__global__ __launch_bounds__(512) void ema_reduce(
    const float* __restrict__ partial, float* __restrict__ out,
    const float* th1, const float* ph1, const float* th2, const float* ph2,
    const float* w1p, const float* w2p, const float* bgp) {
    const int b = blockIdx.x;
    const int d = threadIdx.x;
    const float g   = compute_g(th1, ph1, th2, ph2, w1p, w2p, bgp);
    const float omg = 1.0f - g;
    float s = 0.f;
    for (int c = 0; c < NC; ++c) {
        if (g * powf(omg, (float)c) < WCUT) break;   // same float expr -> same predicate
        s += partial[((size_t)c * BB + b) * DD + d];
    }
    out[(size_t)b * DD + d] = s;
}

extern "C" void kernel_launch(void* const* d_in, const int* in_sizes, int n_in,
                              void* d_out, int out_size, void* d_ws, size_t ws_size,
                              hipStream_t stream) {
    const float* x   = (const float*)d_in[0];
    const float* Pw  = (const float*)d_in[1];
    const float* Ww  = (const float*)d_in[2];
    const float* Wb  = (const float*)d_in[3];
    const float* bv  = (const float*)d_in[4];
    const float* lng = (const float*)d_in[5];
    const float* lnb = (const float*)d_in[6];
    // d_in[7] = alpha: unused — alpha*cal_scalar is d-constant; LayerNorm cancels it exactly.
    const float* th1 = (const float*)d_in[8];
    const float* ph1 = (const float*)d_in[9];
    const float* th2 = (const float*)d_in[10];
    const float* ph2 = (const float*)d_in[11];
    const float* w1  = (const float*)d_in[12];
    const float* w2  = (const float*)d_in[13];
    const float* bg  = (const float*)d_in[14];

    float* CT      = (float*)d_ws;              // [F][D] = 1 MB (transposed merged weight)
    float* partial = CT + (size_t)DD * FF;      // [NC][BB][DD] = 4 MB

    dim3 wmgrid(32, 16);
    weight_merge<<<wmgrid, 256, 0, stream>>>(Pw, Ww, CT);

    dim3 grid(NC, NBG);
    fused_base<<<grid, 512, 0, stream>>>(x, CT, Wb, bv, lng, lnb,
                                         th1, ph1, th2, ph2, w1, w2, bg, partial);
    ema_reduce<<<BB, DD, 0, stream>>>(partial, (float*)d_out,
                                      th1, ph1, th2, ph2, w1, w2, bg);
}

// Round 5
// 55.325 us; speedup vs baseline: 11.8385x; 1.4200x over previous
//
#include <hip/hip_runtime.h>

// Problem constants (fixed by the reference).
#define BB   32
#define TT   2048
#define FF   512
#define KK   1024
#define DD   512
#define NCMAX 512        // max active timesteps: g>=0.05 -> g*(1-g)^c >= 1e-12 needs c <= 481
#define LN_EPS 1e-5f
#define WCUT 1e-12f      // drop terms with EMA weight < 1e-12 (bounded err ~5e-11 << 5.8e-2 thr)

// g = clip(sigmoid(w1*cos(t1)cos(p1) + w2*cos(t2)cos(p2) + b_g), 0.05, 0.75)
__device__ __forceinline__ float compute_g(const float* th1, const float* ph1,
                                           const float* th2, const float* ph2,
                                           const float* w1, const float* w2,
                                           const float* bg) {
    float z1 = cosf(*th1) * cosf(*ph1);
    float z2 = cosf(*th2) * cosf(*ph2);
    float s  = (*w1) * z1 + (*w2) * z2 + (*bg);
    float sg = 1.0f / (1.0f + expf(-s));
    return fminf(fmaxf(sg, 0.05f), 0.75f);
}

// ---- CT[f][d] = sum_k Ww[d][k] * Pw[k][f]  (C transposed so downstream reads coalesce) ----
// Tile: 16 d x 32 f over K=1024. Grid (32,16) = 512 blocks, 256 threads.
__global__ __launch_bounds__(256) void weight_merge(
    const float* __restrict__ Pw, const float* __restrict__ Ww,
    float* __restrict__ CT) {
    __shared__ float pws[64][32];    // Pw k-chunk x f-tile (8 KB)
    __shared__ float tr[32][17];     // transpose staging (f x d, padded)

    const int tid = threadIdx.x;
    const int d0  = blockIdx.x * 16;
    const int f0  = blockIdx.y * 32;
    const int dl  = tid >> 4;        // 0..15
    const int fl  = tid & 15;        // 0..15 -> f-pair
    const float* wwr = Ww + (size_t)(d0 + dl) * KK;

    float acc0 = 0.f, acc1 = 0.f;
    for (int k0 = 0; k0 < KK; k0 += 64) {
        {   // stage Pw[k0..k0+63][f0..f0+31], coalesced float4
            const int row = tid >> 3;
            const int col = (tid & 7) * 4;
            *(float4*)&pws[row][col]      = *(const float4*)(Pw + (size_t)(k0 + row)      * FF + f0 + col);
            *(float4*)&pws[row + 32][col] = *(const float4*)(Pw + (size_t)(k0 + row + 32) * FF + f0 + col);
        }
        __syncthreads();
        #pragma unroll 4
        for (int k = 0; k < 64; k += 4) {
            const float4 wv = *(const float4*)(wwr + k0 + k);   // 16 lanes share a row (L1 broadcast)
            const float2 p0 = *(const float2*)&pws[k + 0][fl * 2];
            const float2 p1 = *(const float2*)&pws[k + 1][fl * 2];
            const float2 p2 = *(const float2*)&pws[k + 2][fl * 2];
            const float2 p3 = *(const float2*)&pws[k + 3][fl * 2];
            acc0 += wv.x * p0.x + wv.y * p1.x + wv.z * p2.x + wv.w * p3.x;
            acc1 += wv.x * p0.y + wv.y * p1.y + wv.z * p2.y + wv.w * p3.y;
        }
        __syncthreads();
    }
    tr[fl * 2][dl]     = acc0;
    tr[fl * 2 + 1][dl] = acc1;
    __syncthreads();
    if (tid < 128) {
        const int f  = tid >> 2;
        const int dq = (tid & 3) * 4;
        float4 v = make_float4(tr[f][dq], tr[f][dq + 1], tr[f][dq + 2], tr[f][dq + 3]);
        *(float4*)(CT + (size_t)(f0 + f) * DD + d0 + dq) = v;
    }
}

// ---- base[c*32+b][d] = x[b][t(c)] . CT[:,d] + (Wb[d]+b[d])  for active c ----
// Grid: (16, NCMAX). blockIdx.x: dt = >>2 (128-d tile), bg = &3 (8-batch group).
// 256 threads: fs = tid>>5 (8 f-slices of 64), dl = tid&31 (x4 -> 128 d).
// alpha*cal_scalar is d-constant -> cancels exactly in the later LayerNorm -> never computed.
__global__ __launch_bounds__(256) void base_gemm(
    const float* __restrict__ x,   const float* __restrict__ CT,
    const float* __restrict__ Wb,  const float* __restrict__ bvec,
    const float* th1, const float* ph1, const float* th2, const float* ph2,
    const float* w1p, const float* w2p, const float* bgp,
    float* __restrict__ base) {

    const int c = blockIdx.y;
    const float g   = compute_g(th1, ph1, th2, ph2, w1p, w2p, bgp);
    const float omg = 1.0f - g;
    if (g * powf(omg, (float)c) < WCUT) return;   // inactive timestep (monotone in c)

    __shared__ float xs[8][FF];          // 16 KB
    __shared__ float red[8][8][128];     // 32 KB: [f-slice][row][d-local]

    const int tid = threadIdx.x;
    const int dt  = blockIdx.x >> 2;
    const int bg  = blockIdx.x & 3;
    const int t   = TT - 1 - c;

    // stage 8 x rows (coalesced float4)
    for (int i = tid; i < 8 * FF / 4; i += 256) {
        const int r  = i >> 7;
        const int f4 = (i & 127) * 4;
        *(float4*)&xs[r][f4] =
            *(const float4*)(x + ((size_t)(bg * 8 + r) * TT + t) * FF + f4);
    }
    __syncthreads();

    const int fs = tid >> 5;
    const int dl = tid & 31;
    const float* ctp = CT + (size_t)(fs * 64) * DD + dt * 128 + dl * 4;

    float acc[8][4];
    #pragma unroll
    for (int r = 0; r < 8; ++r)
        #pragma unroll
        for (int q = 0; q < 4; ++q) acc[r][q] = 0.f;

    #pragma unroll 4
    for (int f = 0; f < 64; ++f) {
        const float4 cv = *(const float4*)(ctp + (size_t)f * DD);
        #pragma unroll
        for (int r = 0; r < 8; ++r) {
            const float xv = xs[r][fs * 64 + f];   // LDS broadcast
            acc[r][0] += xv * cv.x;
            acc[r][1] += xv * cv.y;
            acc[r][2] += xv * cv.z;
            acc[r][3] += xv * cv.w;
        }
    }
    #pragma unroll
    for (int r = 0; r < 8; ++r)
        *(float4*)&red[fs][r][dl * 4] = *(float4*)acc[r];
    __syncthreads();

    // reduce over the 8 f-slices; add bias; write base row
    {
        const int r2 = tid >> 5;             // 0..7
        const int d  = dt * 128 + dl * 4;
        float4 s = make_float4(0.f, 0.f, 0.f, 0.f);
        #pragma unroll
        for (int q = 0; q < 8; ++q) {
            const float4 v = *(const float4*)&red[q][r2][dl * 4];
            s.x += v.x; s.y += v.y; s.z += v.z; s.w += v.w;
        }
        const float4 wb = *(const float4*)(Wb + d);
        const float4 bb = *(const float4*)(bvec + d);
        s.x += wb.x + bb.x; s.y += wb.y + bb.y; s.z += wb.z + bb.z; s.w += wb.w + bb.w;
        *(float4*)(base + ((size_t)c * BB + bg * 8 + r2) * DD + d) = s;
    }
}

// ---- LN + EMA + reduce, one block per batch b. 8 waves; wave w owns c = w, w+8, ... ----
__global__ __launch_bounds__(512) void ln_ema(
    const float* __restrict__ base,
    const float* __restrict__ lng, const float* __restrict__ lnb,
    const float* th1, const float* ph1, const float* th2, const float* ph2,
    const float* w1p, const float* w2p, const float* bgp,
    float* __restrict__ out) {

    __shared__ float hred[8][DD];   // 16 KB

    const int b    = blockIdx.x;
    const int tid  = threadIdx.x;
    const int w    = tid >> 6;
    const int l    = tid & 63;

    const float g   = compute_g(th1, ph1, th2, ph2, w1p, w2p, bgp);
    const float omg = 1.0f - g;

    float ga[8], be[8];
    #pragma unroll
    for (int i = 0; i < 8; ++i) { ga[i] = lng[l * 8 + i]; be[i] = lnb[l * 8 + i]; }

    float hacc[8] = {0.f, 0.f, 0.f, 0.f, 0.f, 0.f, 0.f, 0.f};

    for (int c = w; c < NCMAX; c += 8) {
        const float wj = g * powf(omg, (float)c);   // identical expr as base_gemm predicate
        if (wj < WCUT) break;                       // wave-uniform (scalar g)
        const float* bp = base + ((size_t)c * BB + b) * DD + l * 8;
        const float4 v0 = *(const float4*)(bp);
        const float4 v1 = *(const float4*)(bp + 4);
        float S = v0.x + v0.y + v0.z + v0.w + v1.x + v1.y + v1.z + v1.w;
        float Q = v0.x*v0.x + v0.y*v0.y + v0.z*v0.z + v0.w*v0.w
                + v1.x*v1.x + v1.y*v1.y + v1.z*v1.z + v1.w*v1.w;
        #pragma unroll
        for (int off = 32; off >= 1; off >>= 1) {
            S += __shfl_xor(S, off);
            Q += __shfl_xor(Q, off);
        }
        const float mu   = S * (1.0f / DD);
        const float rstd = rsqrtf(Q * (1.0f / DD) - mu * mu + LN_EPS);
        const float vv[8] = {v0.x, v0.y, v0.z, v0.w, v1.x, v1.y, v1.z, v1.w};
        #pragma unroll
        for (int i = 0; i < 8; ++i)
            hacc[i] += wj * ((vv[i] - mu) * rstd * ga[i] + be[i]);
    }

    #pragma unroll
    for (int i = 0; i < 8; ++i) hred[w][l * 8 + i] = hacc[i];
    __syncthreads();

    // final cross-wave sum: thread d
    {
        const int d = tid;
        float s = 0.f;
        #pragma unroll
        for (int q = 0; q < 8; ++q) s += hred[q][d];
        out[(size_t)b * DD + d] = s;
    }
}

extern "C" void kernel_launch(void* const* d_in, const int* in_sizes, int n_in,
                              void* d_out, int out_size, void* d_ws, size_t ws_size,
                              hipStream_t stream) {
    const float* x   = (const float*)d_in[0];
    const float* Pw  = (const float*)d_in[1];
    const float* Ww  = (const float*)d_in[2];
    const float* Wb  = (const float*)d_in[3];
    const float* bv  = (const float*)d_in[4];
    const float* lng = (const float*)d_in[5];
    const float* lnb = (const float*)d_in[6];
    // d_in[7] = alpha: unused — alpha*cal_scalar is d-constant; LayerNorm cancels it exactly.
    const float* th1 = (const float*)d_in[8];
    const float* ph1 = (const float*)d_in[9];
    const float* th2 = (const float*)d_in[10];
    const float* ph2 = (const float*)d_in[11];
    const float* w1  = (const float*)d_in[12];
    const float* w2  = (const float*)d_in[13];
    const float* bg  = (const float*)d_in[14];

    float* CT   = (float*)d_ws;                 // [F][D] = 1 MB
    float* base = CT + (size_t)DD * FF;         // [NCMAX][BB][DD] = 33.5 MB

    dim3 wmgrid(32, 16);
    weight_merge<<<wmgrid, 256, 0, stream>>>(Pw, Ww, CT);

    dim3 bgrid(16, NCMAX);
    base_gemm<<<bgrid, 256, 0, stream>>>(x, CT, Wb, bv,
                                         th1, ph1, th2, ph2, w1, w2, bg, base);

    ln_ema<<<BB, 512, 0, stream>>>(base, lng, lnb,
                                   th1, ph1, th2, ph2, w1, w2, bg, (float*)d_out);
}

// Round 6
// 53.953 us; speedup vs baseline: 12.1395x; 1.0254x over previous
//
#include <hip/hip_runtime.h>

// Problem constants (fixed by the reference).
#define BB   32
#define TT   2048
#define FF   512
#define KK   1024
#define DD   512
#define NCMAX 512        // max active timesteps: g>=0.05 -> g*(1-g)^c >= 1e-12 needs c <= 481
#define LN_EPS 1e-5f
#define WCUT 1e-12f      // drop terms with EMA weight < 1e-12 (bounded err ~5e-11 << 5.8e-2 thr)

// g = clip(sigmoid(w1*cos(t1)cos(p1) + w2*cos(t2)cos(p2) + b_g), 0.05, 0.75)
__device__ __forceinline__ float compute_g(const float* th1, const float* ph1,
                                           const float* th2, const float* ph2,
                                           const float* w1, const float* w2,
                                           const float* bg) {
    float z1 = cosf(*th1) * cosf(*ph1);
    float z2 = cosf(*th2) * cosf(*ph2);
    float s  = (*w1) * z1 + (*w2) * z2 + (*bg);
    float sg = 1.0f / (1.0f + expf(-s));
    return fminf(fmaxf(sg, 0.05f), 0.75f);
}

// ---- CT[f][d] = sum_k Ww[d][k] * Pw[k][f]; block (0,0) also precomputes the EMA
//      weight table wj[c] = g*(1-g)^c and n_active (count of wj >= WCUT). ----
// Tile: 16 d x 32 f over K=1024. Grid (32,16) = 512 blocks, 256 threads.
__global__ __launch_bounds__(256) void weight_merge(
    const float* __restrict__ Pw, const float* __restrict__ Ww,
    float* __restrict__ CT, float* __restrict__ wj, int* __restrict__ nact,
    const float* th1, const float* ph1, const float* th2, const float* ph2,
    const float* w1p, const float* w2p, const float* bgp) {
    __shared__ float pws[64][32];    // Pw k-chunk x f-tile (8 KB)
    __shared__ float tr[32][17];     // transpose staging (f x d, padded)
    __shared__ int   cnt4[4];

    const int tid = threadIdx.x;

    // ---- setup prelude: only block (0,0). All downstream kernels use wj/nact. ----
    if (blockIdx.x == 0 && blockIdx.y == 0) {
        const float g   = compute_g(th1, ph1, th2, ph2, w1p, w2p, bgp);
        const float omg = 1.0f - g;
        const float w0  = g * powf(omg, (float)tid);
        const float w1  = g * powf(omg, (float)(tid + 256));
        wj[tid]       = w0;
        wj[tid + 256] = w1;
        const unsigned long long m0 = __ballot(w0 >= WCUT);
        const unsigned long long m1 = __ballot(w1 >= WCUT);
        if ((tid & 63) == 0) cnt4[tid >> 6] = __popcll(m0) + __popcll(m1);
        __syncthreads();
        if (tid == 0) *nact = cnt4[0] + cnt4[1] + cnt4[2] + cnt4[3];
    }

    const int d0  = blockIdx.x * 16;
    const int f0  = blockIdx.y * 32;
    const int dl  = tid >> 4;        // 0..15
    const int fl  = tid & 15;        // 0..15 -> f-pair
    const float* wwr = Ww + (size_t)(d0 + dl) * KK;

    float acc0 = 0.f, acc1 = 0.f;
    for (int k0 = 0; k0 < KK; k0 += 64) {
        {   // stage Pw[k0..k0+63][f0..f0+31], coalesced float4
            const int row = tid >> 3;
            const int col = (tid & 7) * 4;
            *(float4*)&pws[row][col]      = *(const float4*)(Pw + (size_t)(k0 + row)      * FF + f0 + col);
            *(float4*)&pws[row + 32][col] = *(const float4*)(Pw + (size_t)(k0 + row + 32) * FF + f0 + col);
        }
        __syncthreads();
        #pragma unroll 4
        for (int k = 0; k < 64; k += 4) {
            const float4 wv = *(const float4*)(wwr + k0 + k);   // 16 lanes share a row (L1 broadcast)
            const float2 p0 = *(const float2*)&pws[k + 0][fl * 2];
            const float2 p1 = *(const float2*)&pws[k + 1][fl * 2];
            const float2 p2 = *(const float2*)&pws[k + 2][fl * 2];
            const float2 p3 = *(const float2*)&pws[k + 3][fl * 2];
            acc0 += wv.x * p0.x + wv.y * p1.x + wv.z * p2.x + wv.w * p3.x;
            acc1 += wv.x * p0.y + wv.y * p1.y + wv.z * p2.y + wv.w * p3.y;
        }
        __syncthreads();
    }
    tr[fl * 2][dl]     = acc0;
    tr[fl * 2 + 1][dl] = acc1;
    __syncthreads();
    if (tid < 128) {
        const int f  = tid >> 2;
        const int dq = (tid & 3) * 4;
        float4 v = make_float4(tr[f][dq], tr[f][dq + 1], tr[f][dq + 2], tr[f][dq + 3]);
        *(float4*)(CT + (size_t)(f0 + f) * DD + d0 + dq) = v;
    }
}

// ---- base_part[fh][c][b][d] = x[b][t(c)][fh-half] . CT[fh-half][d]  (pure GEMM, no bias) ----
// Grid (32, 64): bx -> fh = bx>>4 (2 f-halves), bg = (bx>>2)&3 (4 batch-groups of 8),
// dt = bx&3 (4 d-tiles of 128). by = c-slot; block loops c = slot + 64j while c < n_active.
// alpha*cal_scalar is d-constant -> cancels exactly in the later LayerNorm -> never computed.
__global__ __launch_bounds__(256) void base_gemm(
    const float* __restrict__ x,   const float* __restrict__ CT,
    const int* __restrict__ nact,
    float* __restrict__ base) {

    const int nv = *nact;
    if ((int)blockIdx.y >= nv) return;     // cheap early-exit (no transcendentals)

    __shared__ float xs[8][256];           // 8 KB: 8 rows x f-half
    __shared__ float red[4][8][128];       // 16 KB: [f-slice][row][d-local]

    const int tid = threadIdx.x;
    const int fh  = blockIdx.x >> 4;
    const int bg  = (blockIdx.x >> 2) & 3;
    const int dt  = blockIdx.x & 3;

    const int rg  = tid >> 7;              // 2 row-groups of 4
    const int fs  = (tid >> 5) & 3;        // 4 f-slices of 64
    const int dl  = tid & 31;              // d-quad lane

    for (int c = blockIdx.y; c < nv; c += 64) {
        const int t = TT - 1 - c;

        // stage 8 x rows (f-half), coalesced float4
        for (int i = tid; i < 8 * 256 / 4; i += 256) {
            const int r  = i >> 6;
            const int f4 = (i & 63) * 4;
            *(float4*)&xs[r][f4] =
                *(const float4*)(x + ((size_t)(bg * 8 + r) * TT + t) * FF + fh * 256 + f4);
        }
        __syncthreads();

        float4 acc[4];
        #pragma unroll
        for (int r = 0; r < 4; ++r) acc[r] = make_float4(0.f, 0.f, 0.f, 0.f);

        const float* ctp = CT + (size_t)(fh * 256 + fs * 64) * DD + dt * 128 + dl * 4;
        #pragma unroll 4
        for (int f = 0; f < 64; f += 4) {
            const float4 cv0 = *(const float4*)(ctp + (size_t)(f + 0) * DD);
            const float4 cv1 = *(const float4*)(ctp + (size_t)(f + 1) * DD);
            const float4 cv2 = *(const float4*)(ctp + (size_t)(f + 2) * DD);
            const float4 cv3 = *(const float4*)(ctp + (size_t)(f + 3) * DD);
            #pragma unroll
            for (int r = 0; r < 4; ++r) {
                const float4 xv = *(const float4*)&xs[rg * 4 + r][fs * 64 + f];  // LDS b128 broadcast
                acc[r].x += xv.x * cv0.x + xv.y * cv1.x + xv.z * cv2.x + xv.w * cv3.x;
                acc[r].y += xv.x * cv0.y + xv.y * cv1.y + xv.z * cv2.y + xv.w * cv3.y;
                acc[r].z += xv.x * cv0.z + xv.y * cv1.z + xv.z * cv2.z + xv.w * cv3.z;
                acc[r].w += xv.x * cv0.w + xv.y * cv1.w + xv.z * cv2.w + xv.w * cv3.w;
            }
        }
        #pragma unroll
        for (int r = 0; r < 4; ++r)
            *(float4*)&red[fs][rg * 4 + r][dl * 4] = acc[r];
        __syncthreads();

        // reduce over 4 f-slices; write raw base part
        {
            const int r2 = tid >> 5;       // 0..7
            float4 s = make_float4(0.f, 0.f, 0.f, 0.f);
            #pragma unroll
            for (int q = 0; q < 4; ++q) {
                const float4 v = *(const float4*)&red[q][r2][dl * 4];
                s.x += v.x; s.y += v.y; s.z += v.z; s.w += v.w;
            }
            *(float4*)(base + (((size_t)fh * NCMAX + c) * BB + bg * 8 + r2) * DD + dt * 128 + dl * 4) = s;
        }
        __syncthreads();   // protect xs/red for next c
    }
}

// ---- LN + EMA + reduce: one block per batch. 8 waves; wave w owns c = w, w+8, ... ----
__global__ __launch_bounds__(512) void ln_ema(
    const float* __restrict__ base,
    const float* __restrict__ Wb,  const float* __restrict__ bvec,
    const float* __restrict__ lng, const float* __restrict__ lnb,
    const float* __restrict__ wj,  const int* __restrict__ nact,
    float* __restrict__ out) {

    __shared__ float hred[8][DD];   // 16 KB

    const int b   = blockIdx.x;
    const int tid = threadIdx.x;
    const int w   = tid >> 6;
    const int l   = tid & 63;
    const int nv  = *nact;

    float ga[8], be[8], bi[8];
    #pragma unroll
    for (int i = 0; i < 8; ++i) {
        ga[i] = lng[l * 8 + i];
        be[i] = lnb[l * 8 + i];
        bi[i] = Wb[l * 8 + i] + bvec[l * 8 + i];
    }

    float hacc[8] = {0.f, 0.f, 0.f, 0.f, 0.f, 0.f, 0.f, 0.f};

    for (int c = w; c < nv; c += 8) {
        const float wjc = wj[c];
        const float* bp0 = base + ((size_t)c * BB + b) * DD + l * 8;
        const float* bp1 = bp0 + (size_t)NCMAX * BB * DD;
        const float4 u0 = *(const float4*)(bp0);
        const float4 u1 = *(const float4*)(bp0 + 4);
        const float4 q0 = *(const float4*)(bp1);
        const float4 q1 = *(const float4*)(bp1 + 4);
        float vv[8];
        vv[0] = u0.x + q0.x + bi[0]; vv[1] = u0.y + q0.y + bi[1];
        vv[2] = u0.z + q0.z + bi[2]; vv[3] = u0.w + q0.w + bi[3];
        vv[4] = u1.x + q1.x + bi[4]; vv[5] = u1.y + q1.y + bi[5];
        vv[6] = u1.z + q1.z + bi[6]; vv[7] = u1.w + q1.w + bi[7];

        float S = 0.f, Q = 0.f;
        #pragma unroll
        for (int i = 0; i < 8; ++i) { S += vv[i]; Q += vv[i] * vv[i]; }
        #pragma unroll
        for (int off = 32; off >= 1; off >>= 1) {
            S += __shfl_xor(S, off);
            Q += __shfl_xor(Q, off);
        }
        const float mu   = S * (1.0f / DD);
        const float rstd = rsqrtf(Q * (1.0f / DD) - mu * mu + LN_EPS);
        #pragma unroll
        for (int i = 0; i < 8; ++i)
            hacc[i] += wjc * ((vv[i] - mu) * rstd * ga[i] + be[i]);
    }

    #pragma unroll
    for (int i = 0; i < 8; ++i) hred[w][l * 8 + i] = hacc[i];
    __syncthreads();

    {
        const int d = tid;
        float s = 0.f;
        #pragma unroll
        for (int q = 0; q < 8; ++q) s += hred[q][d];
        out[(size_t)b * DD + d] = s;
    }
}

extern "C" void kernel_launch(void* const* d_in, const int* in_sizes, int n_in,
                              void* d_out, int out_size, void* d_ws, size_t ws_size,
                              hipStream_t stream) {
    const float* x   = (const float*)d_in[0];
    const float* Pw  = (const float*)d_in[1];
    const float* Ww  = (const float*)d_in[2];
    const float* Wb  = (const float*)d_in[3];
    const float* bv  = (const float*)d_in[4];
    const float* lng = (const float*)d_in[5];
    const float* lnb = (const float*)d_in[6];
    // d_in[7] = alpha: unused — alpha*cal_scalar is d-constant; LayerNorm cancels it exactly.
    const float* th1 = (const float*)d_in[8];
    const float* ph1 = (const float*)d_in[9];
    const float* th2 = (const float*)d_in[10];
    const float* ph2 = (const float*)d_in[11];
    const float* w1  = (const float*)d_in[12];
    const float* w2  = (const float*)d_in[13];
    const float* bg  = (const float*)d_in[14];

    float* CT   = (float*)d_ws;                    // [F][D] = 1 MB
    float* wj   = CT + (size_t)DD * FF;            // [512] weight table
    int*   nact = (int*)(wj + 512);                // active-count
    float* base = wj + 1024;                       // [2][NCMAX][BB][DD] = 67 MB

    dim3 wmgrid(32, 16);
    weight_merge<<<wmgrid, 256, 0, stream>>>(Pw, Ww, CT, wj, nact,
                                             th1, ph1, th2, ph2, w1, w2, bg);

    dim3 bgrid(32, 64);
    base_gemm<<<bgrid, 256, 0, stream>>>(x, CT, nact, base);

    ln_ema<<<BB, 512, 0, stream>>>(base, Wb, bv, lng, lnb, wj, nact, (float*)d_out);
}

// Round 7
// 41.585 us; speedup vs baseline: 15.7501x; 1.2974x over previous
//
#include <hip/hip_runtime.h>

// Problem constants (fixed by the reference).
#define BB   32
#define TT   2048
#define FF   512
#define KK   1024
#define DD   512
#define NCMAX 512        // max active timesteps: g>=0.05 -> g*(1-g)^c >= 1e-12 needs c <= 481
#define LN_EPS 1e-5f
#define WCUT 1e-12f      // drop terms with EMA weight < 1e-12 (bounded err ~5e-11 << 5.8e-2 thr)

typedef __attribute__((ext_vector_type(8))) short bf16x8;
typedef __attribute__((ext_vector_type(4))) float f32x4;

// g = clip(sigmoid(w1*cos(t1)cos(p1) + w2*cos(t2)cos(p2) + b_g), 0.05, 0.75)
__device__ __forceinline__ float compute_g(const float* th1, const float* ph1,
                                           const float* th2, const float* ph2,
                                           const float* w1, const float* w2,
                                           const float* bg) {
    float z1 = cosf(*th1) * cosf(*ph1);
    float z2 = cosf(*th2) * cosf(*ph2);
    float s  = (*w1) * z1 + (*w2) * z2 + (*bg);
    float sg = 1.0f / (1.0f + expf(-s));
    return fminf(fmaxf(sg, 0.05f), 0.75f);
}

// fp32 -> bf16 bits, round-to-nearest-even
__device__ __forceinline__ ushort f2bf(float x) {
    unsigned u = __float_as_uint(x);
    u += 0x7FFFu + ((u >> 16) & 1u);
    return (ushort)(u >> 16);
}

// ---- MFMA weight merge: CT[f][d] = sum_k Ww[d][k] * Pw[k][f] (bf16 in, fp32 acc). ----
// 64 blocks (8x8 of 64d x 64f tiles), 256 threads = 4 waves (2x2, each 32x32 output).
// LDS layout (both operands identical, "octet-major"): tile[8 k-octets][64 slots][8 bf16],
// slot = row ^ (octet&3). Frag read: lane l (ll=l&15, lg=l>>4), octet oq=ks*4+lg:
//   b128 at [oq][ (row0+ll)^lg ] -> conflict-free (sequential 16B slots per lane group).
// The slot-XOR is a pure storage bijection (same on write & read) -> invisible to MFMA.
// k-pairing: A and B use the SAME k->slot convention, so MFMA contracts matching k's.
// D layout (HW-verified m89): col = lane&15 (-> f), row = (lane>>4)*4+reg (-> d):
// gives CT (transposed C) directly as per-lane float4 stores.
// Block (0) also precomputes the EMA weight table wj[c] and n_active.
__global__ __launch_bounds__(256) void weight_merge(
    const float* __restrict__ Pw, const float* __restrict__ Ww,
    float* __restrict__ CT, float* __restrict__ wj, int* __restrict__ nact,
    const float* th1, const float* ph1, const float* th2, const float* ph2,
    const float* w1p, const float* w2p, const float* bgp) {

    __shared__ __align__(16) ushort As[8 * 64 * 8];   // Ww tile, 8 KB
    __shared__ __align__(16) ushort Bs[8 * 64 * 8];   // Pw^T tile, 8 KB
    __shared__ int cnt4[4];

    const int tid = threadIdx.x;

    // ---- setup prelude: only block 0. All downstream kernels use wj/nact. ----
    if (blockIdx.x == 0) {
        const float g   = compute_g(th1, ph1, th2, ph2, w1p, w2p, bgp);
        const float omg = 1.0f - g;
        const float w0  = g * powf(omg, (float)tid);
        const float w1  = g * powf(omg, (float)(tid + 256));
        wj[tid]       = w0;
        wj[tid + 256] = w1;
        const unsigned long long m0 = __ballot(w0 >= WCUT);
        const unsigned long long m1 = __ballot(w1 >= WCUT);
        if ((tid & 63) == 0) cnt4[tid >> 6] = __popcll(m0) + __popcll(m1);
        __syncthreads();
        if (tid == 0) *nact = cnt4[0] + cnt4[1] + cnt4[2] + cnt4[3];
    }

    const int d0   = (blockIdx.x >> 3) * 64;
    const int f0   = (blockIdx.x & 7) * 64;
    const int wave = tid >> 6;
    const int lane = tid & 63;
    const int wm2  = wave >> 1;        // wave's d-half
    const int wn2  = wave & 1;         // wave's f-half
    const int lg   = lane >> 4;        // k-octet group 0..3
    const int ll   = lane & 15;        // free-index lane

    const int cw = tid & 15;           // staging: column group
    const int rq = tid >> 4;           // staging: row group

    f32x4 acc00 = {0.f, 0.f, 0.f, 0.f}, acc01 = {0.f, 0.f, 0.f, 0.f};
    f32x4 acc10 = {0.f, 0.f, 0.f, 0.f}, acc11 = {0.f, 0.f, 0.f, 0.f};

    float4 wwreg[4], pwa[2], pwb[2];

    // register-staged load of one 64-k chunk (issued a chunk ahead to hide L2 latency)
#define STAGE_LOAD(kkv) do {                                                          \
        _Pragma("unroll")                                                             \
        for (int i = 0; i < 4; ++i)                                                   \
            wwreg[i] = *(const float4*)(Ww + (size_t)(d0 + rq + i * 16) * KK + (kkv) + cw * 4); \
        _Pragma("unroll")                                                             \
        for (int i = 0; i < 2; ++i) {                                                 \
            const int kr = (rq + i * 16) * 2;                                         \
            pwa[i] = *(const float4*)(Pw + (size_t)((kkv) + kr)     * FF + f0 + cw * 4); \
            pwb[i] = *(const float4*)(Pw + (size_t)((kkv) + kr + 1) * FF + f0 + cw * 4); \
        }                                                                             \
    } while (0)

    STAGE_LOAD(0);

    for (int kk = 0; kk < KK; kk += 64) {
        // ---- convert + write LDS (from regs) ----
        {
            const int qa = cw >> 1, ha = cw & 1;            // k-octet, half
            #pragma unroll
            for (int i = 0; i < 4; ++i) {
                const int r = rq + i * 16;                  // d-row 0..63
                ushort4 b;
                b.x = f2bf(wwreg[i].x); b.y = f2bf(wwreg[i].y);
                b.z = f2bf(wwreg[i].z); b.w = f2bf(wwreg[i].w);
                *(ushort4*)&As[qa * 512 + ((r ^ (qa & 3)) << 3) + ha * 4] = b;
            }
            #pragma unroll
            for (int i = 0; i < 2; ++i) {
                const int kr = (rq + i * 16) * 2;           // k-pair row 0..62
                const int q  = kr >> 3, j = kr & 7, q3 = q & 3;
                const float fa[4] = {pwa[i].x, pwa[i].y, pwa[i].z, pwa[i].w};
                const float fb[4] = {pwb[i].x, pwb[i].y, pwb[i].z, pwb[i].w};
                #pragma unroll
                for (int e = 0; e < 4; ++e) {
                    ushort2 p; p.x = f2bf(fa[e]); p.y = f2bf(fb[e]);
                    *(ushort2*)&Bs[q * 512 + (((cw * 4 + e) ^ q3) << 3) + j] = p;
                }
            }
        }
        __syncthreads();

        if (kk + 64 < KK) STAGE_LOAD(kk + 64);   // prefetch next chunk under compute

        // ---- fragments + MFMA ----
        #pragma unroll
        for (int ks = 0; ks < 2; ++ks) {
            const int base = (ks * 4 + lg) * 512;
            const bf16x8 af0 = *(const bf16x8*)&As[base + (((wm2 * 32 +  0 + ll) ^ lg) << 3)];
            const bf16x8 af1 = *(const bf16x8*)&As[base + (((wm2 * 32 + 16 + ll) ^ lg) << 3)];
            const bf16x8 bg0 = *(const bf16x8*)&Bs[base + (((wn2 * 32 +  0 + ll) ^ lg) << 3)];
            const bf16x8 bg1 = *(const bf16x8*)&Bs[base + (((wn2 * 32 + 16 + ll) ^ lg) << 3)];
            acc00 = __builtin_amdgcn_mfma_f32_16x16x32_bf16(af0, bg0, acc00, 0, 0, 0);
            acc01 = __builtin_amdgcn_mfma_f32_16x16x32_bf16(af0, bg1, acc01, 0, 0, 0);
            acc10 = __builtin_amdgcn_mfma_f32_16x16x32_bf16(af1, bg0, acc10, 0, 0, 0);
            acc11 = __builtin_amdgcn_mfma_f32_16x16x32_bf16(af1, bg1, acc11, 0, 0, 0);
        }
        __syncthreads();
    }
#undef STAGE_LOAD

    // ---- epilogue: CT[f][d], lane writes 4 consecutive d (reg 0..3) ----
    {
        const int fb = f0 + wn2 * 32 + ll;
        const int db = d0 + wm2 * 32 + lg * 4;
        *(float4*)(CT + (size_t)(fb     ) * DD + db     ) = make_float4(acc00[0], acc00[1], acc00[2], acc00[3]);
        *(float4*)(CT + (size_t)(fb + 16) * DD + db     ) = make_float4(acc01[0], acc01[1], acc01[2], acc01[3]);
        *(float4*)(CT + (size_t)(fb     ) * DD + db + 16) = make_float4(acc10[0], acc10[1], acc10[2], acc10[3]);
        *(float4*)(CT + (size_t)(fb + 16) * DD + db + 16) = make_float4(acc11[0], acc11[1], acc11[2], acc11[3]);
    }
}

// ---- base_part[fh][c][b][d] = x[b][t(c)][fh-half] . CT[fh-half][d]  (pure GEMM, no bias) ----
// Grid (32, 64): bx -> fh = bx>>4 (2 f-halves), bg = (bx>>2)&3 (4 batch-groups of 8),
// dt = bx&3 (4 d-tiles of 128). by = c-slot; block loops c = slot + 64j while c < n_active.
// alpha*cal_scalar is d-constant -> cancels exactly in the later LayerNorm -> never computed.
__global__ __launch_bounds__(256) void base_gemm(
    const float* __restrict__ x,   const float* __restrict__ CT,
    const int* __restrict__ nact,
    float* __restrict__ base) {

    const int nv = *nact;
    if ((int)blockIdx.y >= nv) return;     // cheap early-exit (no transcendentals)

    __shared__ float xs[8][256];           // 8 KB: 8 rows x f-half
    __shared__ float red[4][8][128];       // 16 KB: [f-slice][row][d-local]

    const int tid = threadIdx.x;
    const int fh  = blockIdx.x >> 4;
    const int bg  = (blockIdx.x >> 2) & 3;
    const int dt  = blockIdx.x & 3;

    const int rg  = tid >> 7;              // 2 row-groups of 4
    const int fs  = (tid >> 5) & 3;        // 4 f-slices of 64
    const int dl  = tid & 31;              // d-quad lane

    for (int c = blockIdx.y; c < nv; c += 64) {
        const int t = TT - 1 - c;

        // stage 8 x rows (f-half), coalesced float4
        for (int i = tid; i < 8 * 256 / 4; i += 256) {
            const int r  = i >> 6;
            const int f4 = (i & 63) * 4;
            *(float4*)&xs[r][f4] =
                *(const float4*)(x + ((size_t)(bg * 8 + r) * TT + t) * FF + fh * 256 + f4);
        }
        __syncthreads();

        float4 acc[4];
        #pragma unroll
        for (int r = 0; r < 4; ++r) acc[r] = make_float4(0.f, 0.f, 0.f, 0.f);

        const float* ctp = CT + (size_t)(fh * 256 + fs * 64) * DD + dt * 128 + dl * 4;
        #pragma unroll 4
        for (int f = 0; f < 64; f += 4) {
            const float4 cv0 = *(const float4*)(ctp + (size_t)(f + 0) * DD);
            const float4 cv1 = *(const float4*)(ctp + (size_t)(f + 1) * DD);
            const float4 cv2 = *(const float4*)(ctp + (size_t)(f + 2) * DD);
            const float4 cv3 = *(const float4*)(ctp + (size_t)(f + 3) * DD);
            #pragma unroll
            for (int r = 0; r < 4; ++r) {
                const float4 xv = *(const float4*)&xs[rg * 4 + r][fs * 64 + f];  // LDS b128 broadcast
                acc[r].x += xv.x * cv0.x + xv.y * cv1.x + xv.z * cv2.x + xv.w * cv3.x;
                acc[r].y += xv.x * cv0.y + xv.y * cv1.y + xv.z * cv2.y + xv.w * cv3.y;
                acc[r].z += xv.x * cv0.z + xv.y * cv1.z + xv.z * cv2.z + xv.w * cv3.z;
                acc[r].w += xv.x * cv0.w + xv.y * cv1.w + xv.z * cv2.w + xv.w * cv3.w;
            }
        }
        #pragma unroll
        for (int r = 0; r < 4; ++r)
            *(float4*)&red[fs][rg * 4 + r][dl * 4] = acc[r];
        __syncthreads();

        // reduce over 4 f-slices; write raw base part
        {
            const int r2 = tid >> 5;       // 0..7
            float4 s = make_float4(0.f, 0.f, 0.f, 0.f);
            #pragma unroll
            for (int q = 0; q < 4; ++q) {
                const float4 v = *(const float4*)&red[q][r2][dl * 4];
                s.x += v.x; s.y += v.y; s.z += v.z; s.w += v.w;
            }
            *(float4*)(base + (((size_t)fh * NCMAX + c) * BB + bg * 8 + r2) * DD + dt * 128 + dl * 4) = s;
        }
        __syncthreads();   // protect xs/red for next c
    }
}

// ---- LN + EMA + reduce: one block per batch. 8 waves; wave w owns c = w, w+8, ... ----
__global__ __launch_bounds__(512) void ln_ema(
    const float* __restrict__ base,
    const float* __restrict__ Wb,  const float* __restrict__ bvec,
    const float* __restrict__ lng, const float* __restrict__ lnb,
    const float* __restrict__ wj,  const int* __restrict__ nact,
    float* __restrict__ out) {

    __shared__ float hred[8][DD];   // 16 KB

    const int b   = blockIdx.x;
    const int tid = threadIdx.x;
    const int w   = tid >> 6;
    const int l   = tid & 63;
    const int nv  = *nact;

    float ga[8], be[8], bi[8];
    #pragma unroll
    for (int i = 0; i < 8; ++i) {
        ga[i] = lng[l * 8 + i];
        be[i] = lnb[l * 8 + i];
        bi[i] = Wb[l * 8 + i] + bvec[l * 8 + i];
    }

    float hacc[8] = {0.f, 0.f, 0.f, 0.f, 0.f, 0.f, 0.f, 0.f};

    for (int c = w; c < nv; c += 8) {
        const float wjc = wj[c];
        const float* bp0 = base + ((size_t)c * BB + b) * DD + l * 8;
        const float* bp1 = bp0 + (size_t)NCMAX * BB * DD;
        const float4 u0 = *(const float4*)(bp0);
        const float4 u1 = *(const float4*)(bp0 + 4);
        const float4 q0 = *(const float4*)(bp1);
        const float4 q1 = *(const float4*)(bp1 + 4);
        float vv[8];
        vv[0] = u0.x + q0.x + bi[0]; vv[1] = u0.y + q0.y + bi[1];
        vv[2] = u0.z + q0.z + bi[2]; vv[3] = u0.w + q0.w + bi[3];
        vv[4] = u1.x + q1.x + bi[4]; vv[5] = u1.y + q1.y + bi[5];
        vv[6] = u1.z + q1.z + bi[6]; vv[7] = u1.w + q1.w + bi[7];

        float S = 0.f, Q = 0.f;
        #pragma unroll
        for (int i = 0; i < 8; ++i) { S += vv[i]; Q += vv[i] * vv[i]; }
        #pragma unroll
        for (int off = 32; off >= 1; off >>= 1) {
            S += __shfl_xor(S, off);
            Q += __shfl_xor(Q, off);
        }
        const float mu   = S * (1.0f / DD);
        const float rstd = rsqrtf(Q * (1.0f / DD) - mu * mu + LN_EPS);
        #pragma unroll
        for (int i = 0; i < 8; ++i)
            hacc[i] += wjc * ((vv[i] - mu) * rstd * ga[i] + be[i]);
    }

    #pragma unroll
    for (int i = 0; i < 8; ++i) hred[w][l * 8 + i] = hacc[i];
    __syncthreads();

    {
        const int d = tid;
        float s = 0.f;
        #pragma unroll
        for (int q = 0; q < 8; ++q) s += hred[q][d];
        out[(size_t)b * DD + d] = s;
    }
}

extern "C" void kernel_launch(void* const* d_in, const int* in_sizes, int n_in,
                              void* d_out, int out_size, void* d_ws, size_t ws_size,
                              hipStream_t stream) {
    const float* x   = (const float*)d_in[0];
    const float* Pw  = (const float*)d_in[1];
    const float* Ww  = (const float*)d_in[2];
    const float* Wb  = (const float*)d_in[3];
    const float* bv  = (const float*)d_in[4];
    const float* lng = (const float*)d_in[5];
    const float* lnb = (const float*)d_in[6];
    // d_in[7] = alpha: unused — alpha*cal_scalar is d-constant; LayerNorm cancels it exactly.
    const float* th1 = (const float*)d_in[8];
    const float* ph1 = (const float*)d_in[9];
    const float* th2 = (const float*)d_in[10];
    const float* ph2 = (const float*)d_in[11];
    const float* w1  = (const float*)d_in[12];
    const float* w2  = (const float*)d_in[13];
    const float* bg  = (const float*)d_in[14];

    float* CT   = (float*)d_ws;                    // [F][D] = 1 MB
    float* wj   = CT + (size_t)DD * FF;            // [512] weight table
    int*   nact = (int*)(wj + 512);                // active-count
    float* base = wj + 1024;                       // [2][NCMAX][BB][DD] = 67 MB

    weight_merge<<<64, 256, 0, stream>>>(Pw, Ww, CT, wj, nact,
                                         th1, ph1, th2, ph2, w1, w2, bg);

    dim3 bgrid(32, 64);
    base_gemm<<<bgrid, 256, 0, stream>>>(x, CT, nact, base);

    ln_ema<<<BB, 512, 0, stream>>>(base, Wb, bv, lng, lnb, wj, nact, (float*)d_out);
}